// Round 3
// baseline (140.249 us; speedup 1.0000x reference)
//
#include <hip/hip_runtime.h>

#define NORM_EPS 1e-12f

__device__ __forceinline__ float bf16_lo_to_f(unsigned u) {
    union { unsigned u; float f; } c; c.u = u << 16; return c.f;
}
__device__ __forceinline__ float bf16_hi_to_f(unsigned u) {
    union { unsigned u; float f; } c; c.u = u & 0xFFFF0000u; return c.f;
}
__device__ __forceinline__ unsigned f_to_bf16_rne(float f) {
    union { float f; unsigned u; } c; c.f = f;
    return (c.u + 0x7FFFu + ((c.u >> 16) & 1u)) >> 16;
}

// Kernel 1: L2-normalize each row, emit bf16 table (norms folded in).
// One 64-lane wave per row; float2/lane in, packed 2xbf16 dword/lane out.
__global__ void norm_bf16_kernel(const float* __restrict__ emb,
                                 unsigned* __restrict__ tbl,   // n_nodes*64 dwords
                                 int n_nodes) {
    int wave = (blockIdx.x * blockDim.x + threadIdx.x) >> 6;
    int lane = threadIdx.x & 63;
    if (wave >= n_nodes) return;
    const float2* p = (const float2*)(emb + (size_t)wave * 128);
    float2 v = p[lane];
    float s = v.x * v.x + v.y * v.y;
    #pragma unroll
    for (int off = 32; off > 0; off >>= 1)
        s += __shfl_xor(s, off);                  // butterfly: all lanes get sum
    float inv = 1.0f / fmaxf(sqrtf(s), NORM_EPS);
    unsigned lo = f_to_bf16_rne(v.x * inv);
    unsigned hi = f_to_bf16_rne(v.y * inv);
    tbl[(size_t)wave * 64 + lane] = lo | (hi << 16);
}

__device__ __forceinline__ float dot8(uint4 a, uint4 b, float4 w0, float4 w1) {
    float s;
    s  = bf16_lo_to_f(a.x) * bf16_lo_to_f(b.x) * w0.x;
    s += bf16_hi_to_f(a.x) * bf16_hi_to_f(b.x) * w0.y;
    s += bf16_lo_to_f(a.y) * bf16_lo_to_f(b.y) * w0.z;
    s += bf16_hi_to_f(a.y) * bf16_hi_to_f(b.y) * w0.w;
    s += bf16_lo_to_f(a.z) * bf16_lo_to_f(b.z) * w1.x;
    s += bf16_hi_to_f(a.z) * bf16_hi_to_f(b.z) * w1.y;
    s += bf16_lo_to_f(a.w) * bf16_lo_to_f(b.w) * w1.z;
    s += bf16_hi_to_f(a.w) * bf16_hi_to_f(b.w) * w1.w;
    return s;
}

// Kernel 2: 16 lanes per edge, 4 edges per lane-group (8 row-gathers in
// flight per thread). Row = 256 B bf16 = 16 lanes x uint4. d in registers.
__global__ void edge_dot_bf16_kernel(const uint4* __restrict__ tbl,
                                     const int* __restrict__ esrc,
                                     const int* __restrict__ edst,
                                     const float* __restrict__ dvec,
                                     const float* __restrict__ scale,
                                     float* __restrict__ out,
                                     int n_edges) {
    int g    = (blockIdx.x * blockDim.x + threadIdx.x) >> 4;   // quad id
    int lane = threadIdx.x & 15;
    int e0 = g * 4;
    if (e0 >= n_edges) return;

    int si[4], di[4];
    #pragma unroll
    for (int k = 0; k < 4; ++k) {
        int e = e0 + k;
        int ec = (e < n_edges) ? e : e0;          // clamp tail to a valid edge
        si[k] = esrc[ec];
        di[k] = edst[ec];
    }

    // 8 independent 256B gathers in flight
    uint4 a[4], b[4];
    #pragma unroll
    for (int k = 0; k < 4; ++k) a[k] = tbl[(size_t)si[k] * 16 + lane];
    #pragma unroll
    for (int k = 0; k < 4; ++k) b[k] = tbl[(size_t)di[k] * 16 + lane];

    const float4* dv = (const float4*)dvec;
    float4 w0 = dv[lane * 2];
    float4 w1 = dv[lane * 2 + 1];

    float acc[4];
    #pragma unroll
    for (int k = 0; k < 4; ++k) acc[k] = dot8(a[k], b[k], w0, w1);

    #pragma unroll
    for (int off = 8; off > 0; off >>= 1) {
        #pragma unroll
        for (int k = 0; k < 4; ++k) acc[k] += __shfl_xor(acc[k], off);
    }

    if (lane == 0) {
        float sc = scale[0];
        #pragma unroll
        for (int k = 0; k < 4; ++k) {
            int e = e0 + k;
            if (e < n_edges) out[e] = acc[k] * sc;
        }
    }
}

extern "C" void kernel_launch(void* const* d_in, const int* in_sizes, int n_in,
                              void* d_out, int out_size, void* d_ws, size_t ws_size,
                              hipStream_t stream) {
    const float* emb   = (const float*)d_in[0];
    const int*   esrc  = (const int*)d_in[1];
    const int*   edst  = (const int*)d_in[2];
    const float* dvec  = (const float*)d_in[3];
    const float* scale = (const float*)d_in[4];
    float*       out   = (float*)d_out;

    int n_nodes = in_sizes[0] / 128;
    int n_edges = in_sizes[1];

    unsigned* tbl = (unsigned*)d_ws;   // n_nodes * 256 B bf16 table (25.6 MB)

    {   // 4 rows per 256-thread block
        int blocks = (n_nodes + 3) / 4;
        norm_bf16_kernel<<<blocks, 256, 0, stream>>>(emb, tbl, n_nodes);
    }
    {
        int n_quads = (n_edges + 3) / 4;                 // 4 edges per 16-lane group
        long long threads = (long long)n_quads * 16;
        int blocks = (int)((threads + 255) / 256);
        edge_dot_bf16_kernel<<<blocks, 256, 0, stream>>>(
            (const uint4*)tbl, esrc, edst, dvec, scale, out, n_edges);
    }
}

// Round 4
// 131.522 us; speedup vs baseline: 1.0664x; 1.0664x over previous
//
#include <hip/hip_runtime.h>

#define NORM_EPS 1e-12f

#if defined(__has_builtin) && __has_builtin(__builtin_amdgcn_sdot4)
__device__ __forceinline__ int sdot4(unsigned a, unsigned b, int c) {
    return __builtin_amdgcn_sdot4((int)a, (int)b, c, false);
}
#else
__device__ __forceinline__ int sdot4(unsigned a, unsigned b, int c) {
    #pragma unroll
    for (int i = 0; i < 4; ++i)
        c += (int)(signed char)(a >> (8 * i)) * (int)(signed char)(b >> (8 * i));
    return c;
}
#endif

// Kernel 1: per row — L2-normalize, build two int8 tables (W = e*d, E = e)
// with per-row absmax scales. One 64-lane wave per row, 2 elems/lane.
__global__ void build_tables_kernel(const float* __restrict__ emb,
                                    const float* __restrict__ dvec,
                                    unsigned short* __restrict__ tblW,  // row*64+lane
                                    unsigned short* __restrict__ tblE,
                                    float* __restrict__ sclW,
                                    float* __restrict__ sclE,
                                    int n_nodes) {
    int row  = (blockIdx.x * blockDim.x + threadIdx.x) >> 6;
    int lane = threadIdx.x & 63;
    if (row >= n_nodes) return;

    const float2* p = (const float2*)(emb + (size_t)row * 128);
    float2 v = p[lane];
    float s = v.x * v.x + v.y * v.y;
    #pragma unroll
    for (int off = 32; off > 0; off >>= 1)
        s += __shfl_xor(s, off);
    float inv = 1.0f / fmaxf(sqrtf(s), NORM_EPS);

    float e0 = v.x * inv, e1 = v.y * inv;
    float2 d2 = ((const float2*)dvec)[lane];
    float w0 = e0 * d2.x, w1 = e1 * d2.y;

    float mW = fmaxf(fabsf(w0), fabsf(w1));
    float mE = fmaxf(fabsf(e0), fabsf(e1));
    #pragma unroll
    for (int off = 32; off > 0; off >>= 1) {
        mW = fmaxf(mW, __shfl_xor(mW, off));
        mE = fmaxf(mE, __shfl_xor(mE, off));
    }

    float qW = (mW > 0.f) ? 127.0f / mW : 0.f;
    float qE = (mE > 0.f) ? 127.0f / mE : 0.f;
    int qw0 = __float2int_rn(w0 * qW), qw1 = __float2int_rn(w1 * qW);
    int qe0 = __float2int_rn(e0 * qE), qe1 = __float2int_rn(e1 * qE);

    tblW[(size_t)row * 64 + lane] =
        (unsigned short)((qw0 & 0xFF) | ((qw1 & 0xFF) << 8));
    tblE[(size_t)row * 64 + lane] =
        (unsigned short)((qe0 & 0xFF) | ((qe1 & 0xFF) << 8));
    if (lane == 0) {
        sclW[row] = mW * (1.0f / 127.0f);
        sclE[row] = mE * (1.0f / 127.0f);
    }
}

// Kernel 2: 8 lanes per edge (128B int8 row = 8 x uint4), 2 edges per group.
// Exact int32 dot via v_dot4_i32_i8, butterfly reduce, per-row scales.
__global__ void edge_dot_i8_kernel(const uint4* __restrict__ tW,
                                   const uint4* __restrict__ tE,
                                   const float* __restrict__ sW,
                                   const float* __restrict__ sE,
                                   const int* __restrict__ esrc,
                                   const int* __restrict__ edst,
                                   const float* __restrict__ scale,
                                   float* __restrict__ out,
                                   int n_edges) {
    int g    = (blockIdx.x * blockDim.x + threadIdx.x) >> 3;
    int lane = threadIdx.x & 7;
    int e0 = g * 2, e1 = e0 + 1;
    if (e0 >= n_edges) return;
    bool has1 = e1 < n_edges;

    int s0 = esrc[e0], t0 = edst[e0];
    int s1 = has1 ? esrc[e1] : s0;
    int t1 = has1 ? edst[e1] : t0;

    // 4 independent 128B row gathers per lane-group
    uint4 a0 = tW[(size_t)s0 * 8 + lane];
    uint4 b0 = tE[(size_t)t0 * 8 + lane];
    uint4 a1 = tW[(size_t)s1 * 8 + lane];
    uint4 b1 = tE[(size_t)t1 * 8 + lane];

    // scale gathers early (tiny L2-resident arrays; same-addr broadcast)
    float ss0 = sW[s0] * sE[t0];
    float ss1 = sW[s1] * sE[t1];

    int i0 = 0, i1 = 0;
    i0 = sdot4(a0.x, b0.x, i0); i0 = sdot4(a0.y, b0.y, i0);
    i0 = sdot4(a0.z, b0.z, i0); i0 = sdot4(a0.w, b0.w, i0);
    i1 = sdot4(a1.x, b1.x, i1); i1 = sdot4(a1.y, b1.y, i1);
    i1 = sdot4(a1.z, b1.z, i1); i1 = sdot4(a1.w, b1.w, i1);

    #pragma unroll
    for (int off = 4; off > 0; off >>= 1) {
        i0 += __shfl_xor(i0, off);
        i1 += __shfl_xor(i1, off);
    }

    if (lane == 0) {
        float sc = scale[0];
        out[e0] = (float)i0 * ss0 * sc;
        if (has1) out[e1] = (float)i1 * ss1 * sc;
    }
}

extern "C" void kernel_launch(void* const* d_in, const int* in_sizes, int n_in,
                              void* d_out, int out_size, void* d_ws, size_t ws_size,
                              hipStream_t stream) {
    const float* emb   = (const float*)d_in[0];
    const int*   esrc  = (const int*)d_in[1];
    const int*   edst  = (const int*)d_in[2];
    const float* dvec  = (const float*)d_in[3];
    const float* scale = (const float*)d_in[4];
    float*       out   = (float*)d_out;

    int n_nodes = in_sizes[0] / 128;
    int n_edges = in_sizes[1];

    // workspace layout (all 16B-aligned for n_nodes=100000)
    char* base = (char*)d_ws;
    size_t tbl_bytes = (size_t)n_nodes * 128;
    unsigned short* tblW = (unsigned short*)base;
    unsigned short* tblE = (unsigned short*)(base + tbl_bytes);
    float*          sclW = (float*)(base + 2 * tbl_bytes);
    float*          sclE = (float*)(base + 2 * tbl_bytes + (size_t)n_nodes * 4);

    {   // 4 rows per 256-thread block
        int blocks = (n_nodes + 3) / 4;
        build_tables_kernel<<<blocks, 256, 0, stream>>>(
            emb, dvec, tblW, tblE, sclW, sclE, n_nodes);
    }
    {   // 2 edges per 8-lane group -> 32 edges per 256-thread block
        int n_groups = (n_edges + 1) / 2;
        long long threads = (long long)n_groups * 8;
        int blocks = (int)((threads + 255) / 256);
        edge_dot_i8_kernel<<<blocks, 256, 0, stream>>>(
            (const uint4*)tblW, (const uint4*)tblE, sclW, sclE,
            esrc, edst, scale, out, n_edges);
    }
}

// Round 5
// 124.691 us; speedup vs baseline: 1.1248x; 1.0548x over previous
//
#include <hip/hip_runtime.h>

#define NORM_EPS 1e-12f

#if defined(__has_builtin) && __has_builtin(__builtin_amdgcn_sdot4)
__device__ __forceinline__ int sdot4(unsigned a, unsigned b, int c) {
    return __builtin_amdgcn_sdot4((int)a, (int)b, c, false);
}
#else
__device__ __forceinline__ int sdot4(unsigned a, unsigned b, int c) {
    #pragma unroll
    for (int i = 0; i < 4; ++i)
        c += (int)(signed char)(a >> (8 * i)) * (int)(signed char)(b >> (8 * i));
    return c;
}
#endif

// Kernel 1: per row — L2-normalize, fold sqrt(|d|) into the row, quantize to
// int8 with per-row absmax scale. E = quant(e*sqrt(|d|)). Only if d has any
// negative entries do we also emit W = quant(e*sqrt(|d|)*sign(d)) (so that
// W.E = e_s e_d d exactly); |W|=|E| so the scale array is shared. A flag word
// tells the edge kernel which table the src side reads.
__global__ void build_tables_kernel(const float* __restrict__ emb,
                                    const float* __restrict__ dvec,
                                    unsigned short* __restrict__ tblE,  // row*64+lane
                                    unsigned short* __restrict__ tblW,
                                    float* __restrict__ scl,
                                    int* __restrict__ flag,
                                    int n_nodes) {
    int row  = (blockIdx.x * blockDim.x + threadIdx.x) >> 6;
    int lane = threadIdx.x & 63;
    if (row >= n_nodes) return;

    const float2* p = (const float2*)(emb + (size_t)row * 128);
    float2 v = p[lane];
    float s = v.x * v.x + v.y * v.y;
    #pragma unroll
    for (int off = 32; off > 0; off >>= 1)
        s += __shfl_xor(s, off);
    float inv = 1.0f / fmaxf(sqrtf(s), NORM_EPS);

    float2 d2 = ((const float2*)dvec)[lane];
    bool neg_lane = (d2.x < 0.0f) || (d2.y < 0.0f);
    int has_neg = (__ballot(neg_lane) != 0ull) ? 1 : 0;     // wave-uniform

    float r0 = sqrtf(fabsf(d2.x)), r1 = sqrtf(fabsf(d2.y));
    float e0 = v.x * inv * r0, e1 = v.y * inv * r1;         // E side

    float m = fmaxf(fabsf(e0), fabsf(e1));
    #pragma unroll
    for (int off = 32; off > 0; off >>= 1)
        m = fmaxf(m, __shfl_xor(m, off));

    float q = (m > 0.f) ? 127.0f / m : 0.f;
    int qe0 = __float2int_rn(e0 * q), qe1 = __float2int_rn(e1 * q);
    tblE[(size_t)row * 64 + lane] =
        (unsigned short)((qe0 & 0xFF) | ((qe1 & 0xFF) << 8));

    if (has_neg) {            // general-d path: sign-folded src-side table
        float w0 = (d2.x < 0.0f) ? -e0 : e0;
        float w1 = (d2.y < 0.0f) ? -e1 : e1;
        int qw0 = __float2int_rn(w0 * q), qw1 = __float2int_rn(w1 * q);
        tblW[(size_t)row * 64 + lane] =
            (unsigned short)((qw0 & 0xFF) | ((qw1 & 0xFF) << 8));
    }
    if (lane == 0) {
        scl[row] = m * (1.0f / 127.0f);
        if (row == 0) flag[0] = has_neg;
    }
}

// Kernel 2: 8 lanes per edge (128B int8 row = 8 x uint4), 2 edges per group.
// Exact int32 dot via sdot4, butterfly reduce, shared per-row scales.
__global__ void edge_dot_i8_kernel(const uint4* __restrict__ tE,
                                   const uint4* __restrict__ tW,
                                   const float* __restrict__ scl,
                                   const int* __restrict__ flag,
                                   const int* __restrict__ esrc,
                                   const int* __restrict__ edst,
                                   const float* __restrict__ scale,
                                   float* __restrict__ out,
                                   int n_edges) {
    int g    = (blockIdx.x * blockDim.x + threadIdx.x) >> 3;
    int lane = threadIdx.x & 7;
    int e0 = g * 2, e1 = e0 + 1;
    if (e0 >= n_edges) return;
    bool has1 = e1 < n_edges;

    // d>=0 everywhere -> src side reads the same table as dst (halved set)
    const uint4* tS = (flag[0] != 0) ? tW : tE;

    int s0 = esrc[e0], t0 = edst[e0];
    int s1 = has1 ? esrc[e1] : s0;
    int t1 = has1 ? edst[e1] : t0;

    // 4 independent 128B row gathers per lane-group
    uint4 a0 = tS[(size_t)s0 * 8 + lane];
    uint4 b0 = tE[(size_t)t0 * 8 + lane];
    uint4 a1 = tS[(size_t)s1 * 8 + lane];
    uint4 b1 = tE[(size_t)t1 * 8 + lane];

    float ss0 = scl[s0] * scl[t0];
    float ss1 = scl[s1] * scl[t1];

    int i0 = 0, i1 = 0;
    i0 = sdot4(a0.x, b0.x, i0); i0 = sdot4(a0.y, b0.y, i0);
    i0 = sdot4(a0.z, b0.z, i0); i0 = sdot4(a0.w, b0.w, i0);
    i1 = sdot4(a1.x, b1.x, i1); i1 = sdot4(a1.y, b1.y, i1);
    i1 = sdot4(a1.z, b1.z, i1); i1 = sdot4(a1.w, b1.w, i1);

    #pragma unroll
    for (int off = 4; off > 0; off >>= 1) {
        i0 += __shfl_xor(i0, off);
        i1 += __shfl_xor(i1, off);
    }

    if (lane == 0) {
        float sc = scale[0];
        out[e0] = (float)i0 * ss0 * sc;
        if (has1) out[e1] = (float)i1 * ss1 * sc;
    }
}

extern "C" void kernel_launch(void* const* d_in, const int* in_sizes, int n_in,
                              void* d_out, int out_size, void* d_ws, size_t ws_size,
                              hipStream_t stream) {
    const float* emb   = (const float*)d_in[0];
    const int*   esrc  = (const int*)d_in[1];
    const int*   edst  = (const int*)d_in[2];
    const float* dvec  = (const float*)d_in[3];
    const float* scale = (const float*)d_in[4];
    float*       out   = (float*)d_out;

    int n_nodes = in_sizes[0] / 128;
    int n_edges = in_sizes[1];

    // workspace layout (16B-aligned for n_nodes=100000)
    char* base = (char*)d_ws;
    size_t tbl_bytes = (size_t)n_nodes * 128;
    unsigned short* tblE = (unsigned short*)base;
    unsigned short* tblW = (unsigned short*)(base + tbl_bytes);
    float*          scl  = (float*)(base + 2 * tbl_bytes);
    int*            flag = (int*)(base + 2 * tbl_bytes + (size_t)n_nodes * 4);

    {   // 4 rows per 256-thread block
        int blocks = (n_nodes + 3) / 4;
        build_tables_kernel<<<blocks, 256, 0, stream>>>(
            emb, dvec, tblE, tblW, scl, flag, n_nodes);
    }
    {   // 2 edges per 8-lane group -> 64 edges per 256-thread block
        int n_groups = (n_edges + 1) / 2;
        long long threads = (long long)n_groups * 8;
        int blocks = (int)((threads + 255) / 256);
        edge_dot_i8_kernel<<<blocks, 256, 0, stream>>>(
            (const uint4*)tblE, (const uint4*)tblW, scl, flag,
            esrc, edst, scale, out, n_edges);
    }
}